// Round 15
// baseline (534.953 us; speedup 1.0000x reference)
//
#include <hip/hip_runtime.h>
#include <cstddef>

typedef _Float16 f16;
typedef f16 f16x8 __attribute__((ext_vector_type(8)));
typedef f16 f16x4 __attribute__((ext_vector_type(4)));
typedef float f32x4 __attribute__((ext_vector_type(4)));

constexpr int NG    = 16;    // graphs
constexpr int NNODE = 96;    // nodes per graph
constexpr int TOTN  = 1536;  // NG*NNODE
constexpr int HD    = 128;   // hidden
constexpr int NEDGE = 24576;
constexpr int NLAY  = 3;
constexpr int NREG  = NG * 6 * 4;  // 384 consumption regions (b, jt, cp)

__device__ __forceinline__ f32x4 mfma16(f16x8 a, f16x8 b, f32x4 c) {
    return __builtin_amdgcn_mfma_f32_16x16x32_f16(a, b, c, 0, 0, 0);
}

// ---------------- embeddings ----------------
__global__ void k_embed_nodes(const int* x, const float* atab, f16* zA) {
    const int v = blockIdx.x, h = threadIdx.x;  // TOTN x 128
    float s = 0.f;
    for (int c = 0; c < 9; ++c)
        s += atab[((size_t)(c * 119 + x[v * 9 + c])) * HD + h];
    const size_t base = ((size_t)(v >> 4) * 32);
    zA[((base + (h >> 3)) * 16 + (v & 15)) * 8 + (h & 7)] = (f16)s;
    zA[((base + 16 + (h >> 3)) * 16 + (v & 15)) * 8 + (h & 7)] = (f16)0.f;
}

__global__ void k_embed_edges(const int* ea, const float* btab, f16* eftsA) {
    const int e = blockIdx.x, h = threadIdx.x;  // NEDGE x 128
    float s = 0.f;
    for (int c = 0; c < 3; ++c)
        s += btab[((size_t)(c * 6 + ea[e * 3 + c])) * HD + h];
    eftsA[(((size_t)(e >> 4) * 16 + (h >> 3)) * 16 + (e & 15)) * 8 + (h & 7)] = (f16)s;
}

// ---------------- winner/permutation machinery ----------------
__global__ void k_init(int* winner, int* winner2, int* eperm, int* cnt, int* base) {
    const int idx = blockIdx.x * 256 + threadIdx.x;  // >= NG*NNODE*NNODE threads
    if (idx < NG * NNODE * NNODE) {
        winner[idx] = -1;
        winner2[idx] = -1;
    }
    if (idx < NEDGE) eperm[idx] = -1;
    if (idx < NREG) { cnt[idx] = 0; base[idx] = 0; }
}

// last-write-wins: largest edge id wins (numpy fancy-assignment semantics)
__global__ void k_winner(const int* esrc, const int* edst, int* winner) {
    const int e = blockIdx.x * 256 + threadIdx.x;  // NEDGE threads
    const int sg = esrc[e];
    const int g = sg / NNODE;
    const int li = sg - g * NNODE;
    const int lj = edst[e] - g * NNODE;
    atomicMax(&winner[((size_t)g * NNODE + li) * NNODE + lj], e);
}

__device__ __forceinline__ int region_of(int idx) {
    const int b = idx / (NNODE * NNODE);
    const int r = idx - b * NNODE * NNODE;
    const int i = r / NNODE, j = r - (r / NNODE) * NNODE;
    return b * 24 + (j >> 4) * 4 + (i / 24);
}

__global__ void k_count(const int* winner, int* cnt) {
    const int idx = blockIdx.x * 256 + threadIdx.x;  // NG*NNODE*NNODE threads
    if (idx < NG * NNODE * NNODE && winner[idx] >= 0)
        atomicAdd(&cnt[region_of(idx)], 1);
}

__global__ void k_scan(const int* cnt, int* base) {
    if (threadIdx.x == 0) {
        int s = 0;
        for (int r = 0; r < NREG; ++r) {
            base[r] = s;
            s += cnt[r];
        }
    }
}

__global__ void k_assign(const int* winner, int* base, int* winner2, int* eperm) {
    const int idx = blockIdx.x * 256 + threadIdx.x;  // NG*NNODE*NNODE threads
    if (idx >= NG * NNODE * NNODE) return;
    const int e = winner[idx];
    if (e >= 0) {
        const int p = atomicAdd(&base[region_of(idx)], 1);
        winner2[idx] = p;
        eperm[e] = p;
    }
}

// ------- weight swizzle: ALL weights -> f16 B-fragment order -------
__global__ void k_wswz(const float* Wm1, const float* Wm2, const float* Wo1,
                       const float* Wred, const float* Wo2, const float* W1,
                       const float* W2, const float* We,
                       f16* sm1, f16* sm2, f16* so1, f16* sred, f16* so2,
                       f16* s1, f16* s2, f16* sme) {
    const int idx = blockIdx.x * 256 + threadIdx.x;  // 1081344 threads
    const int S256 = 6 * 256 * 128;
    const int SRED = 3 * 256 * 128;
    const int S128 = 6 * 128 * 128;
    const float* src;
    f16* dst;
    int rel, sh;
    if (idx < S256)                   { src = Wm1;  dst = sm1;  rel = idx;              sh = 15; }
    else if (idx < 2 * S256)          { src = Wm2;  dst = sm2;  rel = idx - S256;       sh = 15; }
    else if (idx < 3 * S256)          { src = Wo1;  dst = so1;  rel = idx - 2 * S256;   sh = 15; }
    else if (idx < 3 * S256 + SRED)   { src = Wred; dst = sred; rel = idx - 3 * S256;   sh = 15; }
    else if (idx < 3 * S256 + SRED + S128)
        { src = Wo2; dst = so2; rel = idx - 3 * S256 - SRED; sh = 14; }
    else if (idx < 3 * S256 + SRED + 2 * S128)
        { src = W1;  dst = s1;  rel = idx - 3 * S256 - SRED - S128; sh = 14; }
    else if (idx < 3 * S256 + SRED + 3 * S128)
        { src = W2;  dst = s2;  rel = idx - 3 * S256 - SRED - 2 * S128; sh = 14; }
    else if (idx < 3 * S256 + SRED + 4 * S128)
        { src = We;  dst = sme; rel = idx - 3 * S256 - SRED - 3 * S128; sh = 14; }
    else return;
    const int mat = rel >> sh;
    const int r2 = rel & ((1 << sh) - 1);
    const int k = r2 >> 7, n = r2 & 127;
    dst[(size_t)mat * (1 << sh) + (((k >> 3) * 128 + n) << 3) + (k & 7)] = (f16)src[rel];
}

// ------- per-node GEMMs via MFMA (streaming zA): msg1' / msg2 / o1 -------
__global__ __launch_bounds__(256) void k_ngemm(
    const f16* __restrict__ zA,
    const f16* __restrict__ sm1, const f16* __restrict__ sm2, const f16* __restrict__ so1,
    const float* __restrict__ bm1, const float* __restrict__ bm2,
    const float* __restrict__ bme, const float* __restrict__ bmg,
    const float* __restrict__ bo1,
    float* __restrict__ msg1, float* __restrict__ msg2, float* __restrict__ o1buf,
    int layer) {
    const int tid = threadIdx.x, lane = tid & 63, w = tid >> 6;
    const int mr = lane & 15, q = lane >> 4;
    const int t0 = blockIdx.x;  // 64-row tile
    const int wh = blockIdx.y >> 1, s = blockIdx.y & 1, ls = layer * 2 + s;
    const f16* B;
    float* out;
    float bias[8];
    if (wh == 0) {
        B = sm1 + (size_t)ls * 32768; out = msg1 + (size_t)s * TOTN * HD;
        for (int nt = 0; nt < 8; ++nt) {
            const int col = nt * 16 + mr;
            bias[nt] = bm1[ls * HD + col] + bme[ls * HD + col] + bmg[ls * HD + col];
        }
    } else if (wh == 1) {
        B = sm2 + (size_t)ls * 32768; out = msg2 + (size_t)s * TOTN * HD;
        for (int nt = 0; nt < 8; ++nt) bias[nt] = bm2[ls * HD + nt * 16 + mr];
    } else {
        B = so1 + (size_t)ls * 32768; out = o1buf + (size_t)s * TOTN * HD;
        for (int nt = 0; nt < 8; ++nt) bias[nt] = bo1[ls * HD + nt * 16 + mr];
    }
    const size_t tIdx = (size_t)t0 * 4 + w;
    f32x4 acc[8];
#pragma unroll
    for (int nt = 0; nt < 8; ++nt) acc[nt] = (f32x4){0.f, 0.f, 0.f, 0.f};
#pragma unroll
    for (int kt = 0; kt < 8; ++kt) {
        const int kq = kt * 4 + q;
        f16x8 a = *(const f16x8*)&zA[((tIdx * 32 + kq) * 16 + mr) * 8];
        const f16* bp = B + ((size_t)kq * HD) * 8;
#pragma unroll
        for (int nt = 0; nt < 8; ++nt) {
            f16x8 bv = *(const f16x8*)(bp + (nt * 16 + mr) * 8);
            acc[nt] = mfma16(a, bv, acc[nt]);
        }
    }
#pragma unroll
    for (int nt = 0; nt < 8; ++nt) {
        const int col = nt * 16 + mr;
#pragma unroll
        for (int r = 0; r < 4; ++r) {
            const int row = t0 * 64 + w * 16 + q * 4 + r;
            out[(size_t)row * HD + col] = acc[nt][r] + bias[nt];
        }
    }
}

// ------- per-edge GEMM (ALL 6 mats): emsgP[ls][p] = (eftsA @ Wme)[winning e] -------
__global__ __launch_bounds__(256) void k_egemm(
    const f16* __restrict__ eftsA, const f16* __restrict__ sme,
    const int* __restrict__ eperm, f16* __restrict__ emsgP) {
    const int tid = threadIdx.x, lane = tid & 63, w = tid >> 6;
    const int mr = lane & 15, q = lane >> 4;
    const int ls = blockIdx.y;
    const f16* B = sme + (size_t)ls * 16384;
    f32x4 acc[2][8];
#pragma unroll
    for (int mt = 0; mt < 2; ++mt)
#pragma unroll
        for (int nt = 0; nt < 8; ++nt) acc[mt][nt] = (f32x4){0.f, 0.f, 0.f, 0.f};
#pragma unroll
    for (int kt = 0; kt < 4; ++kt) {
        const int kq = kt * 4 + q;
        f16x8 a0 = *(const f16x8*)&eftsA[(((size_t)(blockIdx.x * 8 + 2 * w + 0) * 16 + kq) * 16 + mr) * 8];
        f16x8 a1 = *(const f16x8*)&eftsA[(((size_t)(blockIdx.x * 8 + 2 * w + 1) * 16 + kq) * 16 + mr) * 8];
        const f16* bp = B + ((size_t)kq * HD) * 8;
#pragma unroll
        for (int nt = 0; nt < 8; ++nt) {
            f16x8 bv = *(const f16x8*)(bp + (nt * 16 + mr) * 8);
            acc[0][nt] = mfma16(a0, bv, acc[0][nt]);
            acc[1][nt] = mfma16(a1, bv, acc[1][nt]);
        }
    }
#pragma unroll
    for (int mt = 0; mt < 2; ++mt) {
        const int ebase = blockIdx.x * 128 + (2 * w + mt) * 16 + q * 4;
#pragma unroll
        for (int r = 0; r < 4; ++r) {
            const int p = eperm[ebase + r];
            if (p < 0) continue;
            f16* orow = emsgP + ((size_t)ls * NEDGE + p) * HD;
#pragma unroll
            for (int nt = 0; nt < 8; ++nt)
                orow[nt * 16 + mr] = (f16)acc[mt][nt][r];
        }
    }
}

// ---------- pair MLP v5: register-built P + region-local emsgP gather ----------
// grid (6 jt, NG, 8 zz=cp*2+s); 256 thr; m-tile = 1 i x 16 j; 3 iters x 8 i.
__global__ __launch_bounds__(256) void k_pairs(
    const float* __restrict__ msg1, const float* __restrict__ msg2,
    const f16* __restrict__ emsgP, const int* __restrict__ winner2,
    const f16* __restrict__ w1s, const float* __restrict__ bmlp1,
    const f16* __restrict__ w2s, const float* __restrict__ bmlp2,
    float* __restrict__ maxpart, int layer) {
    __shared__ __align__(16) f16 M2s[24 * 128];   // 6 KB broadcast cache
    __shared__ __align__(16) f16 Qb[128 * 128];   // 32 KB Q round-trip
    const int tid = threadIdx.x, lane = tid & 63, w = tid >> 6;
    const int mr = lane & 15, q = lane >> 4;
    const int jt = blockIdx.x, b = blockIdx.y, zz = blockIdx.z;
    const int cp = zz >> 1, s = zz & 1, ls = layer * 2 + s;
    const int j0 = jt * 16, i0 = cp * 24;
    const f16* EM = emsgP + (size_t)ls * NEDGE * HD;
    const f16* W1 = w1s + (size_t)ls * HD * HD;
    const f16* W2 = w2s + (size_t)ls * HD * HD;
    // ---- preload msg2 rows i0..i0+23 as f16 ----
    for (int idx = tid * 4; idx < 24 * 128; idx += 1024) {
        const int row = idx >> 7, col = idx & 127;
        float4 v = *(const float4*)&msg2[((size_t)s * TOTN + b * NNODE + i0 + row) * HD + col];
        f16x4 h;
        h[0] = (f16)v.x; h[1] = (f16)v.y; h[2] = (f16)v.z; h[3] = (f16)v.w;
        *(f16x4*)&M2s[idx] = h;
    }
    // ---- msg1 fragment (per-lane invariant): j = j0+mr ----
    f16x8 m1f[4];
    {
        const float* m1p = msg1 + ((size_t)s * TOTN + b * NNODE + j0 + mr) * HD;
#pragma unroll
        for (int kt = 0; kt < 4; ++kt) {
            float4 p0 = *(const float4*)(m1p + kt * 32 + q * 8);
            float4 p1 = *(const float4*)(m1p + kt * 32 + q * 8 + 4);
            m1f[kt][0] = (f16)p0.x; m1f[kt][1] = (f16)p0.y;
            m1f[kt][2] = (f16)p0.z; m1f[kt][3] = (f16)p0.w;
            m1f[kt][4] = (f16)p1.x; m1f[kt][5] = (f16)p1.y;
            m1f[kt][6] = (f16)p1.z; m1f[kt][7] = (f16)p1.w;
        }
    }
    // ---- B fragments for this wave's 2 n-tiles ----
    f16x8 Bf1[4][2], Bf2[4][2];
#pragma unroll
    for (int kt = 0; kt < 4; ++kt)
#pragma unroll
        for (int ntl = 0; ntl < 2; ++ntl) {
            const size_t off = ((size_t)(kt * 4 + q) * 128 + (2 * w + ntl) * 16 + mr) * 8;
            Bf1[kt][ntl] = *(const f16x8*)(W1 + off);
            Bf2[kt][ntl] = *(const f16x8*)(W2 + off);
        }
    float b1v[2], b2v[2];
#pragma unroll
    for (int ntl = 0; ntl < 2; ++ntl) {
        const int col = (2 * w + ntl) * 16 + mr;
        b1v[ntl] = bmlp1[ls * HD + col];
        b2v[ntl] = bmlp2[ls * HD + col];
    }
    float maxr[2][4];
#pragma unroll
    for (int ntl = 0; ntl < 2; ++ntl)
#pragma unroll
        for (int r = 0; r < 4; ++r) maxr[ntl][r] = -3.402823466e38f;
    __syncthreads();  // M2s ready

    for (int it = 0; it < 3; ++it) {
        const int ibase = i0 + it * 8;
        int wv[8];
#pragma unroll
        for (int mt = 0; mt < 8; ++mt)
            wv[mt] = winner2[((size_t)b * NNODE + ibase + mt) * NNODE + j0 + mr];
        // ---- GEMM1 with register-built A = relu(m1 + m2 + e) ----
        f32x4 acc[8][2];
#pragma unroll
        for (int mt = 0; mt < 8; ++mt)
#pragma unroll
            for (int ntl = 0; ntl < 2; ++ntl) acc[mt][ntl] = (f32x4){0.f, 0.f, 0.f, 0.f};
#pragma unroll
        for (int kt = 0; kt < 4; ++kt) {
            const int ko = kt * 32 + q * 8;
#pragma unroll
            for (int mt = 0; mt < 8; ++mt) {
                f16x8 m2v = *(const f16x8*)&M2s[(it * 8 + mt) * 128 + ko];
                f16x8 av = m1f[kt] + m2v;
                if (wv[mt] >= 0) {
                    f16x8 ev = *(const f16x8*)&EM[(size_t)wv[mt] * HD + ko];
                    av = av + ev;
                }
#pragma unroll
                for (int u = 0; u < 8; ++u)
                    av[u] = av[u] > (f16)0.f ? av[u] : (f16)0.f;
                acc[mt][0] = mfma16(av, Bf1[kt][0], acc[mt][0]);
                acc[mt][1] = mfma16(av, Bf1[kt][1], acc[mt][1]);
            }
        }
        // ---- write Q = relu(acc + b1) into Qb ----
#pragma unroll
        for (int mt = 0; mt < 8; ++mt)
#pragma unroll
            for (int ntl = 0; ntl < 2; ++ntl) {
                const int col = (2 * w + ntl) * 16 + mr;
                const int kg = col >> 3, kj = col & 7;
#pragma unroll
                for (int r = 0; r < 4; ++r) {
                    float v = fmaxf(acc[mt][ntl][r] + b1v[ntl], 0.f);
                    Qb[((mt * 16 + kg) * 16 + q * 4 + r) * 8 + kj] = (f16)v;
                }
            }
        __syncthreads();
        // ---- GEMM2 + running max over i ----
#pragma unroll
        for (int mt = 0; mt < 8; ++mt)
#pragma unroll
            for (int ntl = 0; ntl < 2; ++ntl) acc[mt][ntl] = (f32x4){0.f, 0.f, 0.f, 0.f};
#pragma unroll
        for (int kt = 0; kt < 4; ++kt) {
#pragma unroll
            for (int mt = 0; mt < 8; ++mt) {
                f16x8 a = *(const f16x8*)&Qb[((mt * 16 + kt * 4 + q) * 16 + mr) * 8];
                acc[mt][0] = mfma16(a, Bf2[kt][0], acc[mt][0]);
                acc[mt][1] = mfma16(a, Bf2[kt][1], acc[mt][1]);
            }
        }
#pragma unroll
        for (int ntl = 0; ntl < 2; ++ntl)
#pragma unroll
            for (int r = 0; r < 4; ++r) {
                float m0 = acc[0][ntl][r];
#pragma unroll
                for (int mt = 1; mt < 8; ++mt) m0 = fmaxf(m0, acc[mt][ntl][r]);
                maxr[ntl][r] = fmaxf(maxr[ntl][r], m0 + b2v[ntl]);
            }
        __syncthreads();  // Qb reads done before next iteration's writes
    }
#pragma unroll
    for (int ntl = 0; ntl < 2; ++ntl) {
        const int col = (2 * w + ntl) * 16 + mr;
#pragma unroll
        for (int r = 0; r < 4; ++r) {
            const int j = j0 + q * 4 + r;
            maxpart[((size_t)zz * TOTN + b * NNODE + j) * HD + col] = maxr[ntl][r];
        }
    }
}

// ---- fused MFMA: maxreduce(8 slices) -> o2 GEMM -> LN -> red GEMM -> hidden/zA ----
__global__ __launch_bounds__(256) void k_pr(
    const float* __restrict__ maxpart, const float* __restrict__ o1buf,
    const f16* __restrict__ so2, const float* __restrict__ bo2,
    const float* __restrict__ lng, const float* __restrict__ lnb,
    const f16* __restrict__ sred, const float* __restrict__ bred,
    float* __restrict__ hiddenf, f16* __restrict__ zA, int layer) {
    __shared__ __align__(16) f16 Af[16384];  // 32 KB, time-shared A1/A2
    const int tid = threadIdx.x, lane = tid & 63, w = tid >> 6;
    const int mr = lane & 15, q = lane >> 4;
    const int row0 = blockIdx.x * 64;
    {
        const int mrow = tid >> 1, half = tid & 1;
        const int sb = mrow >> 6, rl = mrow & 63;
        const int row = row0 + rl;
#pragma unroll
        for (int c8 = 0; c8 < 64; c8 += 8) {
            const int col = half * 64 + c8;
            float mx[8] = {-3.4e38f, -3.4e38f, -3.4e38f, -3.4e38f,
                           -3.4e38f, -3.4e38f, -3.4e38f, -3.4e38f};
#pragma unroll
            for (int ch = 0; ch < 4; ++ch) {
                const float* p = maxpart + ((size_t)(ch * 2 + sb) * TOTN + row) * HD + col;
                float4 u0 = *(const float4*)p;
                float4 u1 = *(const float4*)(p + 4);
                mx[0] = fmaxf(mx[0], u0.x); mx[1] = fmaxf(mx[1], u0.y);
                mx[2] = fmaxf(mx[2], u0.z); mx[3] = fmaxf(mx[3], u0.w);
                mx[4] = fmaxf(mx[4], u1.x); mx[5] = fmaxf(mx[5], u1.y);
                mx[6] = fmaxf(mx[6], u1.z); mx[7] = fmaxf(mx[7], u1.w);
            }
            f16x8 pv;
#pragma unroll
            for (int u = 0; u < 8; ++u) pv[u] = (f16)mx[u];
            *(f16x8*)&Af[(((sb * 4 + (rl >> 4)) * 16 + (col >> 3)) * 16 + (rl & 15)) * 8] = pv;
        }
    }
    __syncthreads();
    const int sw = w >> 1, ls = layer * 2 + sw;
    const f16* B1 = so2 + (size_t)ls * 16384;
    f32x4 acc[2][8];
#pragma unroll
    for (int mt = 0; mt < 2; ++mt)
#pragma unroll
        for (int nt = 0; nt < 8; ++nt) acc[mt][nt] = (f32x4){0.f, 0.f, 0.f, 0.f};
#pragma unroll
    for (int kt = 0; kt < 4; ++kt) {
        const int kq = kt * 4 + q;
        f16x8 a0 = *(const f16x8*)&Af[(((sw * 4 + (w & 1) * 2 + 0) * 16 + kq) * 16 + mr) * 8];
        f16x8 a1 = *(const f16x8*)&Af[(((sw * 4 + (w & 1) * 2 + 1) * 16 + kq) * 16 + mr) * 8];
        const f16* bp = B1 + ((size_t)kq * HD) * 8;
#pragma unroll
        for (int nt = 0; nt < 8; ++nt) {
            f16x8 bv = *(const f16x8*)(bp + (nt * 16 + mr) * 8);
            acc[0][nt] = mfma16(a0, bv, acc[0][nt]);
            acc[1][nt] = mfma16(a1, bv, acc[1][nt]);
        }
    }
    float lngv[8], lnbv[8], bo2v[8];
#pragma unroll
    for (int nt = 0; nt < 8; ++nt) {
        const int col = nt * 16 + mr;
        lngv[nt] = lng[ls * HD + col];
        lnbv[nt] = lnb[ls * HD + col];
        bo2v[nt] = bo2[ls * HD + col];
    }
#pragma unroll
    for (int mt = 0; mt < 2; ++mt) {
#pragma unroll
        for (int nt = 0; nt < 8; ++nt) {
            const int col = nt * 16 + mr;
#pragma unroll
            for (int r = 0; r < 4; ++r) {
                const int rl = (w & 1) * 32 + mt * 16 + q * 4 + r;
                float v = acc[mt][nt][r] + bo2v[nt] +
                          o1buf[((size_t)sw * TOTN + row0 + rl) * HD + col];
                acc[mt][nt][r] = fmaxf(v, 0.f);
            }
        }
#pragma unroll
        for (int r = 0; r < 4; ++r) {
            float su = 0.f, sq = 0.f;
#pragma unroll
            for (int nt = 0; nt < 8; ++nt) {
                su += acc[mt][nt][r];
                sq += acc[mt][nt][r] * acc[mt][nt][r];
            }
#pragma unroll
            for (int mask = 1; mask <= 8; mask <<= 1) {
                su += __shfl_xor(su, mask, 64);
                sq += __shfl_xor(sq, mask, 64);
            }
            const float mean = su * (1.f / 128.f);
            float var = sq * (1.f / 128.f) - mean * mean;
            var = fmaxf(var, 0.f);
            const float rstd = 1.f / sqrtf(var + 1e-5f);
#pragma unroll
            for (int nt = 0; nt < 8; ++nt)
                acc[mt][nt][r] = (acc[mt][nt][r] - mean) * rstd * lngv[nt] + lnbv[nt];
        }
    }
    __syncthreads();
#pragma unroll
    for (int mt = 0; mt < 2; ++mt)
#pragma unroll
        for (int nt = 0; nt < 8; ++nt) {
            const int kg2 = sw * 16 + nt * 2 + (mr >> 3), j2 = mr & 7;
#pragma unroll
            for (int r = 0; r < 4; ++r) {
                const int rl = (w & 1) * 32 + mt * 16 + q * 4 + r;
                Af[(((rl >> 4) * 32 + kg2) * 16 + (rl & 15)) * 8 + j2] = (f16)acc[mt][nt][r];
            }
        }
    __syncthreads();
    const f16* B2 = sred + (size_t)layer * 32768;
    f32x4 a2[8];
#pragma unroll
    for (int nt = 0; nt < 8; ++nt) a2[nt] = (f32x4){0.f, 0.f, 0.f, 0.f};
#pragma unroll
    for (int kt = 0; kt < 8; ++kt) {
        const int kq = kt * 4 + q;
        f16x8 av = *(const f16x8*)&Af[((w * 32 + kq) * 16 + mr) * 8];
        const f16* bp = B2 + ((size_t)kq * HD) * 8;
#pragma unroll
        for (int nt = 0; nt < 8; ++nt) {
            f16x8 bv = *(const f16x8*)(bp + (nt * 16 + mr) * 8);
            a2[nt] = mfma16(av, bv, a2[nt]);
        }
    }
#pragma unroll
    for (int nt = 0; nt < 8; ++nt) {
        const int col = nt * 16 + mr;
        const float bb = bred[layer * HD + col];
#pragma unroll
        for (int r = 0; r < 4; ++r) {
            const int row = row0 + w * 16 + q * 4 + r;
            const float v = a2[nt][r] + bb;
            hiddenf[(size_t)row * HD + col] = v;
            zA[(((size_t)(row >> 4) * 32 + 16 + (col >> 3)) * 16 + (row & 15)) * 8 + (col & 7)] = (f16)v;
        }
    }
}

// ---------------- mean-pool + 2-layer head; float32 output ----------------
__global__ void k_final(const float* hiddenf, const float* Wp1, const float* bp1,
                        const float* Wp2, const float* bp2, float* out) {
    __shared__ float se[128];
    __shared__ float sr[128];
    const int b = blockIdx.x, h = threadIdx.x;
    float acc = 0.f;
    for (int v = 0; v < NNODE; ++v)
        acc += hiddenf[((size_t)b * NNODE + v) * HD + h];
    se[h] = acc * (1.f / 96.f);
    __syncthreads();
    float a2 = bp1[h];
    for (int k = 0; k < 128; ++k)
        a2 += se[k] * Wp1[(size_t)k * HD + h];
    a2 = fmaxf(a2, 0.f);
    sr[h] = a2 * Wp2[h];
    __syncthreads();
    for (int off = 64; off > 0; off >>= 1) {
        if (h < off) sr[h] += sr[h + off];
        __syncthreads();
    }
    if (h == 0) out[b] = sr[0] + bp2[0];
}

extern "C" void kernel_launch(void* const* d_in, const int* in_sizes, int n_in,
                              void* d_out, int out_size, void* d_ws, size_t ws_size,
                              hipStream_t stream) {
    (void)in_sizes; (void)n_in; (void)out_size; (void)ws_size;
    const int* x    = (const int*)d_in[0];
    const int* ea   = (const int*)d_in[1];
    const int* esrc = (const int*)d_in[2];
    const int* edst = (const int*)d_in[3];
    const float* atab = (const float*)d_in[6];
    const float* btab = (const float*)d_in[7];
    const float* Wm1 = (const float*)d_in[8];    const float* bm1 = (const float*)d_in[9];
    const float* Wm2 = (const float*)d_in[10];   const float* bm2 = (const float*)d_in[11];
    const float* Wme = (const float*)d_in[12];   const float* bme = (const float*)d_in[13];
    const float* bmg = (const float*)d_in[15];
    const float* Wmlp1 = (const float*)d_in[16]; const float* bmlp1 = (const float*)d_in[17];
    const float* Wmlp2 = (const float*)d_in[18]; const float* bmlp2 = (const float*)d_in[19];
    const float* Wo1 = (const float*)d_in[20];   const float* bo1 = (const float*)d_in[21];
    const float* Wo2 = (const float*)d_in[22];   const float* bo2 = (const float*)d_in[23];
    const float* lng = (const float*)d_in[24];   const float* lnb = (const float*)d_in[25];
    const float* Wred = (const float*)d_in[26];  const float* bred = (const float*)d_in[27];
    const float* Wp1 = (const float*)d_in[28];   const float* bp1 = (const float*)d_in[29];
    const float* Wp2 = (const float*)d_in[30];   const float* bp2 = (const float*)d_in[31];

    char* cur = (char*)d_ws;
    f16* zA = (f16*)cur;          cur += (size_t)TOTN * 256 * 2;
    float* hiddenf = (float*)cur; cur += (size_t)TOTN * HD * 4;
    f16* eftsA = (f16*)cur;       cur += (size_t)NEDGE * HD * 2;
    f16* emsgP = (f16*)cur;       cur += (size_t)6 * NEDGE * HD * 2;
    float* msg1 = (float*)cur;    cur += (size_t)2 * TOTN * HD * 4;
    float* msg2 = (float*)cur;    cur += (size_t)2 * TOTN * HD * 4;
    float* o1buf = (float*)cur;   cur += (size_t)2 * TOTN * HD * 4;
    float* maxpart = (float*)cur; cur += (size_t)8 * TOTN * HD * 4;
    int* winner = (int*)cur;      cur += (size_t)NG * NNODE * NNODE * 4;
    int* winner2 = (int*)cur;     cur += (size_t)NG * NNODE * NNODE * 4;
    int* eperm = (int*)cur;       cur += (size_t)NEDGE * 4;
    int* cnt = (int*)cur;         cur += (size_t)NREG * 4;
    int* basep = (int*)cur;       cur += (size_t)NREG * 4;
    f16* sw1 = (f16*)cur;         cur += (size_t)6 * HD * HD * 2;
    f16* sw2 = (f16*)cur;         cur += (size_t)6 * HD * HD * 2;
    f16* swme = (f16*)cur;        cur += (size_t)6 * HD * HD * 2;
    f16* swm1 = (f16*)cur;        cur += (size_t)6 * 256 * HD * 2;
    f16* swm2 = (f16*)cur;        cur += (size_t)6 * 256 * HD * 2;
    f16* swo1 = (f16*)cur;        cur += (size_t)6 * 256 * HD * 2;
    f16* swred = (f16*)cur;       cur += (size_t)3 * 256 * HD * 2;
    f16* swo2 = (f16*)cur;        cur += (size_t)6 * HD * HD * 2;

    const int NPAIR = NG * NNODE * NNODE;
    k_init<<<(NPAIR + 255) / 256, 256, 0, stream>>>(winner, winner2, eperm, cnt, basep);
    k_embed_nodes<<<TOTN, 128, 0, stream>>>(x, atab, zA);
    k_embed_edges<<<NEDGE, 128, 0, stream>>>(ea, btab, eftsA);
    k_winner<<<NEDGE / 256, 256, 0, stream>>>(esrc, edst, winner);
    k_count<<<(NPAIR + 255) / 256, 256, 0, stream>>>(winner, cnt);
    k_scan<<<1, 64, 0, stream>>>(cnt, basep);
    k_assign<<<(NPAIR + 255) / 256, 256, 0, stream>>>(winner, basep, winner2, eperm);
    k_wswz<<<4224, 256, 0, stream>>>(Wm1, Wm2, Wo1, Wred, Wo2, Wmlp1, Wmlp2, Wme,
                                     swm1, swm2, swo1, swred, swo2, sw1, sw2, swme);
    k_egemm<<<dim3(192, 6), 256, 0, stream>>>(eftsA, swme, eperm, emsgP);
    for (int layer = 0; layer < NLAY; ++layer) {
        k_ngemm<<<dim3(24, 6), 256, 0, stream>>>(zA, swm1, swm2, swo1,
                                                 bm1, bm2, bme, bmg, bo1,
                                                 msg1, msg2, o1buf, layer);
        k_pairs<<<dim3(6, NG, 8), 256, 0, stream>>>(msg1, msg2, emsgP, winner2,
                                                    sw1, bmlp1, sw2, bmlp2,
                                                    maxpart, layer);
        k_pr<<<24, 256, 0, stream>>>(maxpart, o1buf, swo2, bo2, lng, lnb,
                                     swred, bred, hiddenf, zA, layer);
    }
    k_final<<<NG, 128, 0, stream>>>(hiddenf, Wp1, bp1, Wp2, bp2, (float*)d_out);
}

// Round 16
// 505.666 us; speedup vs baseline: 1.0579x; 1.0579x over previous
//
#include <hip/hip_runtime.h>
#include <cstddef>

typedef _Float16 f16;
typedef f16 f16x8 __attribute__((ext_vector_type(8)));
typedef f16 f16x4 __attribute__((ext_vector_type(4)));
typedef float f32x4 __attribute__((ext_vector_type(4)));

constexpr int NG    = 16;    // graphs
constexpr int NNODE = 96;    // nodes per graph
constexpr int TOTN  = 1536;  // NG*NNODE
constexpr int HD    = 128;   // hidden
constexpr int NEDGE = 24576;
constexpr int NLAY  = 3;
constexpr int NREG  = NG * 6 * 4;  // 384 consumption regions (b, jt, cp)
constexpr int EMCAP = 128;   // LDS window cap (rows); region mean ~59, max ~85
constexpr int EMSTR = 136;   // padded f16 row stride in LDS

__device__ __forceinline__ f32x4 mfma16(f16x8 a, f16x8 b, f32x4 c) {
    return __builtin_amdgcn_mfma_f32_16x16x32_f16(a, b, c, 0, 0, 0);
}

// ---------------- embeddings ----------------
__global__ void k_embed_nodes(const int* x, const float* atab, f16* zA) {
    const int v = blockIdx.x, h = threadIdx.x;  // TOTN x 128
    float s = 0.f;
    for (int c = 0; c < 9; ++c)
        s += atab[((size_t)(c * 119 + x[v * 9 + c])) * HD + h];
    const size_t base = ((size_t)(v >> 4) * 32);
    zA[((base + (h >> 3)) * 16 + (v & 15)) * 8 + (h & 7)] = (f16)s;
    zA[((base + 16 + (h >> 3)) * 16 + (v & 15)) * 8 + (h & 7)] = (f16)0.f;
}

__global__ void k_embed_edges(const int* ea, const float* btab, f16* eftsA) {
    const int e = blockIdx.x, h = threadIdx.x;  // NEDGE x 128
    float s = 0.f;
    for (int c = 0; c < 3; ++c)
        s += btab[((size_t)(c * 6 + ea[e * 3 + c])) * HD + h];
    eftsA[(((size_t)(e >> 4) * 16 + (h >> 3)) * 16 + (e & 15)) * 8 + (h & 7)] = (f16)s;
}

// ---------------- winner/permutation machinery ----------------
__global__ void k_init(int* winner, int* winner2, int* eperm, int* cnt) {
    const int idx = blockIdx.x * 256 + threadIdx.x;
    if (idx < NG * NNODE * NNODE) {
        winner[idx] = -1;
        winner2[idx] = -1;
    }
    if (idx < NEDGE) eperm[idx] = -1;
    if (idx < NREG) cnt[idx] = 0;
}

// last-write-wins: largest edge id wins (numpy fancy-assignment semantics)
__global__ void k_winner(const int* esrc, const int* edst, int* winner) {
    const int e = blockIdx.x * 256 + threadIdx.x;  // NEDGE threads
    const int sg = esrc[e];
    const int g = sg / NNODE;
    const int li = sg - g * NNODE;
    const int lj = edst[e] - g * NNODE;
    atomicMax(&winner[((size_t)g * NNODE + li) * NNODE + lj], e);
}

__device__ __forceinline__ int region_of(int idx) {
    const int b = idx / (NNODE * NNODE);
    const int r = idx - b * NNODE * NNODE;
    const int i = r / NNODE, j = r - (r / NNODE) * NNODE;
    return b * 24 + (j >> 4) * 4 + (i / 24);
}

__global__ void k_count(const int* winner, int* cnt) {
    const int idx = blockIdx.x * 256 + threadIdx.x;
    if (idx < NG * NNODE * NNODE && winner[idx] >= 0)
        atomicAdd(&cnt[region_of(idx)], 1);
}

// parallel exclusive scan over 384 region counts (1 block, 384 threads)
__global__ void k_scan(const int* cnt, int* base, int* base0) {
    __shared__ int tmp[NREG];
    const int t = threadIdx.x;
    tmp[t] = cnt[t];
    __syncthreads();
    for (int off = 1; off < NREG; off <<= 1) {
        int v = (t >= off) ? tmp[t - off] : 0;
        __syncthreads();
        tmp[t] += v;
        __syncthreads();
    }
    const int ex = tmp[t] - cnt[t];
    base[t] = ex;
    base0[t] = ex;
}

__global__ void k_assign(const int* winner, int* base, int* winner2, int* eperm) {
    const int idx = blockIdx.x * 256 + threadIdx.x;
    if (idx >= NG * NNODE * NNODE) return;
    const int e = winner[idx];
    if (e >= 0) {
        const int p = atomicAdd(&base[region_of(idx)], 1);
        winner2[idx] = p;
        eperm[e] = p;
    }
}

// ------- weight swizzle: ALL weights -> f16 B-fragment order -------
__global__ void k_wswz(const float* Wm1, const float* Wm2, const float* Wo1,
                       const float* Wred, const float* Wo2, const float* W1,
                       const float* W2, const float* We,
                       f16* sm1, f16* sm2, f16* so1, f16* sred, f16* so2,
                       f16* s1, f16* s2, f16* sme) {
    const int idx = blockIdx.x * 256 + threadIdx.x;  // 1081344 threads
    const int S256 = 6 * 256 * 128;
    const int SRED = 3 * 256 * 128;
    const int S128 = 6 * 128 * 128;
    const float* src;
    f16* dst;
    int rel, sh;
    if (idx < S256)                   { src = Wm1;  dst = sm1;  rel = idx;              sh = 15; }
    else if (idx < 2 * S256)          { src = Wm2;  dst = sm2;  rel = idx - S256;       sh = 15; }
    else if (idx < 3 * S256)          { src = Wo1;  dst = so1;  rel = idx - 2 * S256;   sh = 15; }
    else if (idx < 3 * S256 + SRED)   { src = Wred; dst = sred; rel = idx - 3 * S256;   sh = 15; }
    else if (idx < 3 * S256 + SRED + S128)
        { src = Wo2; dst = so2; rel = idx - 3 * S256 - SRED; sh = 14; }
    else if (idx < 3 * S256 + SRED + 2 * S128)
        { src = W1;  dst = s1;  rel = idx - 3 * S256 - SRED - S128; sh = 14; }
    else if (idx < 3 * S256 + SRED + 3 * S128)
        { src = W2;  dst = s2;  rel = idx - 3 * S256 - SRED - 2 * S128; sh = 14; }
    else if (idx < 3 * S256 + SRED + 4 * S128)
        { src = We;  dst = sme; rel = idx - 3 * S256 - SRED - 3 * S128; sh = 14; }
    else return;
    const int mat = rel >> sh;
    const int r2 = rel & ((1 << sh) - 1);
    const int k = r2 >> 7, n = r2 & 127;
    dst[(size_t)mat * (1 << sh) + (((k >> 3) * 128 + n) << 3) + (k & 7)] = (f16)src[rel];
}

// ------- per-node GEMMs via MFMA (streaming zA): msg1' / msg2 / o1 -------
__global__ __launch_bounds__(256) void k_ngemm(
    const f16* __restrict__ zA,
    const f16* __restrict__ sm1, const f16* __restrict__ sm2, const f16* __restrict__ so1,
    const float* __restrict__ bm1, const float* __restrict__ bm2,
    const float* __restrict__ bme, const float* __restrict__ bmg,
    const float* __restrict__ bo1,
    float* __restrict__ msg1, float* __restrict__ msg2, float* __restrict__ o1buf,
    int layer) {
    const int tid = threadIdx.x, lane = tid & 63, w = tid >> 6;
    const int mr = lane & 15, q = lane >> 4;
    const int t0 = blockIdx.x;  // 64-row tile
    const int wh = blockIdx.y >> 1, s = blockIdx.y & 1, ls = layer * 2 + s;
    const f16* B;
    float* out;
    float bias[8];
    if (wh == 0) {
        B = sm1 + (size_t)ls * 32768; out = msg1 + (size_t)s * TOTN * HD;
        for (int nt = 0; nt < 8; ++nt) {
            const int col = nt * 16 + mr;
            bias[nt] = bm1[ls * HD + col] + bme[ls * HD + col] + bmg[ls * HD + col];
        }
    } else if (wh == 1) {
        B = sm2 + (size_t)ls * 32768; out = msg2 + (size_t)s * TOTN * HD;
        for (int nt = 0; nt < 8; ++nt) bias[nt] = bm2[ls * HD + nt * 16 + mr];
    } else {
        B = so1 + (size_t)ls * 32768; out = o1buf + (size_t)s * TOTN * HD;
        for (int nt = 0; nt < 8; ++nt) bias[nt] = bo1[ls * HD + nt * 16 + mr];
    }
    const size_t tIdx = (size_t)t0 * 4 + w;
    f32x4 acc[8];
#pragma unroll
    for (int nt = 0; nt < 8; ++nt) acc[nt] = (f32x4){0.f, 0.f, 0.f, 0.f};
#pragma unroll
    for (int kt = 0; kt < 8; ++kt) {
        const int kq = kt * 4 + q;
        f16x8 a = *(const f16x8*)&zA[((tIdx * 32 + kq) * 16 + mr) * 8];
        const f16* bp = B + ((size_t)kq * HD) * 8;
#pragma unroll
        for (int nt = 0; nt < 8; ++nt) {
            f16x8 bv = *(const f16x8*)(bp + (nt * 16 + mr) * 8);
            acc[nt] = mfma16(a, bv, acc[nt]);
        }
    }
#pragma unroll
    for (int nt = 0; nt < 8; ++nt) {
        const int col = nt * 16 + mr;
#pragma unroll
        for (int r = 0; r < 4; ++r) {
            const int row = t0 * 64 + w * 16 + q * 4 + r;
            out[(size_t)row * HD + col] = acc[nt][r] + bias[nt];
        }
    }
}

// ------- per-edge GEMM (ALL 6 mats): emsgP[ls][p] = (eftsA @ Wme)[winning e] -------
__global__ __launch_bounds__(256) void k_egemm(
    const f16* __restrict__ eftsA, const f16* __restrict__ sme,
    const int* __restrict__ eperm, f16* __restrict__ emsgP) {
    const int tid = threadIdx.x, lane = tid & 63, w = tid >> 6;
    const int mr = lane & 15, q = lane >> 4;
    const int ls = blockIdx.y;
    const f16* B = sme + (size_t)ls * 16384;
    f32x4 acc[2][8];
#pragma unroll
    for (int mt = 0; mt < 2; ++mt)
#pragma unroll
        for (int nt = 0; nt < 8; ++nt) acc[mt][nt] = (f32x4){0.f, 0.f, 0.f, 0.f};
#pragma unroll
    for (int kt = 0; kt < 4; ++kt) {
        const int kq = kt * 4 + q;
        f16x8 a0 = *(const f16x8*)&eftsA[(((size_t)(blockIdx.x * 8 + 2 * w + 0) * 16 + kq) * 16 + mr) * 8];
        f16x8 a1 = *(const f16x8*)&eftsA[(((size_t)(blockIdx.x * 8 + 2 * w + 1) * 16 + kq) * 16 + mr) * 8];
        const f16* bp = B + ((size_t)kq * HD) * 8;
#pragma unroll
        for (int nt = 0; nt < 8; ++nt) {
            f16x8 bv = *(const f16x8*)(bp + (nt * 16 + mr) * 8);
            acc[0][nt] = mfma16(a0, bv, acc[0][nt]);
            acc[1][nt] = mfma16(a1, bv, acc[1][nt]);
        }
    }
#pragma unroll
    for (int mt = 0; mt < 2; ++mt) {
        const int ebase = blockIdx.x * 128 + (2 * w + mt) * 16 + q * 4;
#pragma unroll
        for (int r = 0; r < 4; ++r) {
            const int p = eperm[ebase + r];
            if (p < 0) continue;
            f16* orow = emsgP + ((size_t)ls * NEDGE + p) * HD;
#pragma unroll
            for (int nt = 0; nt < 8; ++nt)
                orow[nt * 16 + mr] = (f16)acc[mt][nt][r];
        }
    }
}

// ---------- pair MLP v6: LDS-prefetched edge window + register-built P ----------
// grid (6 jt, NG, 8 zz=cp*2+s); 256 thr; m-tile = 1 i x 16 j; 3 iters x 8 i.
__global__ __launch_bounds__(256) void k_pairs(
    const float* __restrict__ msg1, const float* __restrict__ msg2,
    const f16* __restrict__ emsgP, const int* __restrict__ winner2,
    const int* __restrict__ cnt0, const int* __restrict__ base0,
    const f16* __restrict__ w1s, const float* __restrict__ bmlp1,
    const f16* __restrict__ w2s, const float* __restrict__ bmlp2,
    float* __restrict__ maxpart, int layer) {
    __shared__ __align__(16) f16 M2s[24 * 128];        // 6 KB broadcast cache
    __shared__ __align__(16) f16 Qb[128 * 128];        // 32 KB Q round-trip
    __shared__ __align__(16) f16 EMs[EMCAP * EMSTR];   // 34 KB edge window
    const int tid = threadIdx.x, lane = tid & 63, w = tid >> 6;
    const int mr = lane & 15, q = lane >> 4;
    const int jt = blockIdx.x, b = blockIdx.y, zz = blockIdx.z;
    const int cp = zz >> 1, s = zz & 1, ls = layer * 2 + s;
    const int j0 = jt * 16, i0 = cp * 24;
    const f16* EM = emsgP + (size_t)ls * NEDGE * HD;
    const f16* W1 = w1s + (size_t)ls * HD * HD;
    const f16* W2 = w2s + (size_t)ls * HD * HD;
    const int reg = b * 24 + jt * 4 + cp;
    const int rbase = base0[reg];
    const int rcnt = cnt0[reg];
    // ---- stream edge window into LDS (contiguous after permutation) ----
    {
        const int lim = (rcnt < EMCAP ? rcnt : EMCAP) * 16;
        for (int idx = tid; idx < lim; idx += 256) {
            const int row = idx >> 4, seg = idx & 15;
            *(f16x8*)&EMs[row * EMSTR + seg * 8] =
                *(const f16x8*)&EM[((size_t)(rbase + row)) * HD + seg * 8];
        }
    }
    // ---- preload msg2 rows i0..i0+23 as f16 ----
    for (int idx = tid * 4; idx < 24 * 128; idx += 1024) {
        const int row = idx >> 7, col = idx & 127;
        float4 v = *(const float4*)&msg2[((size_t)s * TOTN + b * NNODE + i0 + row) * HD + col];
        f16x4 h;
        h[0] = (f16)v.x; h[1] = (f16)v.y; h[2] = (f16)v.z; h[3] = (f16)v.w;
        *(f16x4*)&M2s[idx] = h;
    }
    // ---- msg1 fragment (per-lane invariant): j = j0+mr ----
    f16x8 m1f[4];
    {
        const float* m1p = msg1 + ((size_t)s * TOTN + b * NNODE + j0 + mr) * HD;
#pragma unroll
        for (int kt = 0; kt < 4; ++kt) {
            float4 p0 = *(const float4*)(m1p + kt * 32 + q * 8);
            float4 p1 = *(const float4*)(m1p + kt * 32 + q * 8 + 4);
            m1f[kt][0] = (f16)p0.x; m1f[kt][1] = (f16)p0.y;
            m1f[kt][2] = (f16)p0.z; m1f[kt][3] = (f16)p0.w;
            m1f[kt][4] = (f16)p1.x; m1f[kt][5] = (f16)p1.y;
            m1f[kt][6] = (f16)p1.z; m1f[kt][7] = (f16)p1.w;
        }
    }
    // ---- B fragments for this wave's 2 n-tiles ----
    f16x8 Bf1[4][2], Bf2[4][2];
#pragma unroll
    for (int kt = 0; kt < 4; ++kt)
#pragma unroll
        for (int ntl = 0; ntl < 2; ++ntl) {
            const size_t off = ((size_t)(kt * 4 + q) * 128 + (2 * w + ntl) * 16 + mr) * 8;
            Bf1[kt][ntl] = *(const f16x8*)(W1 + off);
            Bf2[kt][ntl] = *(const f16x8*)(W2 + off);
        }
    float b1v[2], b2v[2];
#pragma unroll
    for (int ntl = 0; ntl < 2; ++ntl) {
        const int col = (2 * w + ntl) * 16 + mr;
        b1v[ntl] = bmlp1[ls * HD + col];
        b2v[ntl] = bmlp2[ls * HD + col];
    }
    float maxr[2][4];
#pragma unroll
    for (int ntl = 0; ntl < 2; ++ntl)
#pragma unroll
        for (int r = 0; r < 4; ++r) maxr[ntl][r] = -3.402823466e38f;
    __syncthreads();  // EMs + M2s ready

    for (int it = 0; it < 3; ++it) {
        const int ibase = i0 + it * 8;
        int wv[8];
#pragma unroll
        for (int mt = 0; mt < 8; ++mt)
            wv[mt] = winner2[((size_t)b * NNODE + ibase + mt) * NNODE + j0 + mr];
        // ---- GEMM1 with register-built A = relu(m1 + m2 + e) ----
        f32x4 acc[8][2];
#pragma unroll
        for (int mt = 0; mt < 8; ++mt)
#pragma unroll
            for (int ntl = 0; ntl < 2; ++ntl) acc[mt][ntl] = (f32x4){0.f, 0.f, 0.f, 0.f};
#pragma unroll
        for (int kt = 0; kt < 4; ++kt) {
            const int ko = kt * 32 + q * 8;
#pragma unroll
            for (int mt = 0; mt < 8; ++mt) {
                f16x8 m2v = *(const f16x8*)&M2s[(it * 8 + mt) * 128 + ko];
                f16x8 av = m1f[kt] + m2v;
                if (wv[mt] >= 0) {
                    const int lp = wv[mt] - rbase;
                    const f16* ep = (lp < EMCAP) ? &EMs[lp * EMSTR + ko]
                                                 : &EM[(size_t)wv[mt] * HD + ko];
                    f16x8 ev = *(const f16x8*)ep;
                    av = av + ev;
                }
#pragma unroll
                for (int u = 0; u < 8; ++u)
                    av[u] = av[u] > (f16)0.f ? av[u] : (f16)0.f;
                acc[mt][0] = mfma16(av, Bf1[kt][0], acc[mt][0]);
                acc[mt][1] = mfma16(av, Bf1[kt][1], acc[mt][1]);
            }
        }
        // ---- write Q = relu(acc + b1) into Qb ----
#pragma unroll
        for (int mt = 0; mt < 8; ++mt)
#pragma unroll
            for (int ntl = 0; ntl < 2; ++ntl) {
                const int col = (2 * w + ntl) * 16 + mr;
                const int kg = col >> 3, kj = col & 7;
#pragma unroll
                for (int r = 0; r < 4; ++r) {
                    float v = fmaxf(acc[mt][ntl][r] + b1v[ntl], 0.f);
                    Qb[((mt * 16 + kg) * 16 + q * 4 + r) * 8 + kj] = (f16)v;
                }
            }
        __syncthreads();
        // ---- GEMM2 + running max over i ----
#pragma unroll
        for (int mt = 0; mt < 8; ++mt)
#pragma unroll
            for (int ntl = 0; ntl < 2; ++ntl) acc[mt][ntl] = (f32x4){0.f, 0.f, 0.f, 0.f};
#pragma unroll
        for (int kt = 0; kt < 4; ++kt) {
#pragma unroll
            for (int mt = 0; mt < 8; ++mt) {
                f16x8 a = *(const f16x8*)&Qb[((mt * 16 + kt * 4 + q) * 16 + mr) * 8];
                acc[mt][0] = mfma16(a, Bf2[kt][0], acc[mt][0]);
                acc[mt][1] = mfma16(a, Bf2[kt][1], acc[mt][1]);
            }
        }
#pragma unroll
        for (int ntl = 0; ntl < 2; ++ntl)
#pragma unroll
            for (int r = 0; r < 4; ++r) {
                float m0 = acc[0][ntl][r];
#pragma unroll
                for (int mt = 1; mt < 8; ++mt) m0 = fmaxf(m0, acc[mt][ntl][r]);
                maxr[ntl][r] = fmaxf(maxr[ntl][r], m0 + b2v[ntl]);
            }
        __syncthreads();  // Qb reads done before next iteration's writes
    }
#pragma unroll
    for (int ntl = 0; ntl < 2; ++ntl) {
        const int col = (2 * w + ntl) * 16 + mr;
#pragma unroll
        for (int r = 0; r < 4; ++r) {
            const int j = j0 + q * 4 + r;
            maxpart[((size_t)zz * TOTN + b * NNODE + j) * HD + col] = maxr[ntl][r];
        }
    }
}

// ---- fused MFMA: maxreduce(8 slices) -> o2 GEMM -> LN -> red GEMM -> hidden/zA ----
__global__ __launch_bounds__(256) void k_pr(
    const float* __restrict__ maxpart, const float* __restrict__ o1buf,
    const f16* __restrict__ so2, const float* __restrict__ bo2,
    const float* __restrict__ lng, const float* __restrict__ lnb,
    const f16* __restrict__ sred, const float* __restrict__ bred,
    float* __restrict__ hiddenf, f16* __restrict__ zA, int layer) {
    __shared__ __align__(16) f16 Af[16384];  // 32 KB, time-shared A1/A2
    const int tid = threadIdx.x, lane = tid & 63, w = tid >> 6;
    const int mr = lane & 15, q = lane >> 4;
    const int row0 = blockIdx.x * 64;
    {
        const int mrow = tid >> 1, half = tid & 1;
        const int sb = mrow >> 6, rl = mrow & 63;
        const int row = row0 + rl;
#pragma unroll
        for (int c8 = 0; c8 < 64; c8 += 8) {
            const int col = half * 64 + c8;
            float mx[8] = {-3.4e38f, -3.4e38f, -3.4e38f, -3.4e38f,
                           -3.4e38f, -3.4e38f, -3.4e38f, -3.4e38f};
#pragma unroll
            for (int ch = 0; ch < 4; ++ch) {
                const float* p = maxpart + ((size_t)(ch * 2 + sb) * TOTN + row) * HD + col;
                float4 u0 = *(const float4*)p;
                float4 u1 = *(const float4*)(p + 4);
                mx[0] = fmaxf(mx[0], u0.x); mx[1] = fmaxf(mx[1], u0.y);
                mx[2] = fmaxf(mx[2], u0.z); mx[3] = fmaxf(mx[3], u0.w);
                mx[4] = fmaxf(mx[4], u1.x); mx[5] = fmaxf(mx[5], u1.y);
                mx[6] = fmaxf(mx[6], u1.z); mx[7] = fmaxf(mx[7], u1.w);
            }
            f16x8 pv;
#pragma unroll
            for (int u = 0; u < 8; ++u) pv[u] = (f16)mx[u];
            *(f16x8*)&Af[(((sb * 4 + (rl >> 4)) * 16 + (col >> 3)) * 16 + (rl & 15)) * 8] = pv;
        }
    }
    __syncthreads();
    const int sw = w >> 1, ls = layer * 2 + sw;
    const f16* B1 = so2 + (size_t)ls * 16384;
    f32x4 acc[2][8];
#pragma unroll
    for (int mt = 0; mt < 2; ++mt)
#pragma unroll
        for (int nt = 0; nt < 8; ++nt) acc[mt][nt] = (f32x4){0.f, 0.f, 0.f, 0.f};
#pragma unroll
    for (int kt = 0; kt < 4; ++kt) {
        const int kq = kt * 4 + q;
        f16x8 a0 = *(const f16x8*)&Af[(((sw * 4 + (w & 1) * 2 + 0) * 16 + kq) * 16 + mr) * 8];
        f16x8 a1 = *(const f16x8*)&Af[(((sw * 4 + (w & 1) * 2 + 1) * 16 + kq) * 16 + mr) * 8];
        const f16* bp = B1 + ((size_t)kq * HD) * 8;
#pragma unroll
        for (int nt = 0; nt < 8; ++nt) {
            f16x8 bv = *(const f16x8*)(bp + (nt * 16 + mr) * 8);
            acc[0][nt] = mfma16(a0, bv, acc[0][nt]);
            acc[1][nt] = mfma16(a1, bv, acc[1][nt]);
        }
    }
    float lngv[8], lnbv[8], bo2v[8];
#pragma unroll
    for (int nt = 0; nt < 8; ++nt) {
        const int col = nt * 16 + mr;
        lngv[nt] = lng[ls * HD + col];
        lnbv[nt] = lnb[ls * HD + col];
        bo2v[nt] = bo2[ls * HD + col];
    }
#pragma unroll
    for (int mt = 0; mt < 2; ++mt) {
#pragma unroll
        for (int nt = 0; nt < 8; ++nt) {
            const int col = nt * 16 + mr;
#pragma unroll
            for (int r = 0; r < 4; ++r) {
                const int rl = (w & 1) * 32 + mt * 16 + q * 4 + r;
                float v = acc[mt][nt][r] + bo2v[nt] +
                          o1buf[((size_t)sw * TOTN + row0 + rl) * HD + col];
                acc[mt][nt][r] = fmaxf(v, 0.f);
            }
        }
#pragma unroll
        for (int r = 0; r < 4; ++r) {
            float su = 0.f, sq = 0.f;
#pragma unroll
            for (int nt = 0; nt < 8; ++nt) {
                su += acc[mt][nt][r];
                sq += acc[mt][nt][r] * acc[mt][nt][r];
            }
#pragma unroll
            for (int mask = 1; mask <= 8; mask <<= 1) {
                su += __shfl_xor(su, mask, 64);
                sq += __shfl_xor(sq, mask, 64);
            }
            const float mean = su * (1.f / 128.f);
            float var = sq * (1.f / 128.f) - mean * mean;
            var = fmaxf(var, 0.f);
            const float rstd = 1.f / sqrtf(var + 1e-5f);
#pragma unroll
            for (int nt = 0; nt < 8; ++nt)
                acc[mt][nt][r] = (acc[mt][nt][r] - mean) * rstd * lngv[nt] + lnbv[nt];
        }
    }
    __syncthreads();
#pragma unroll
    for (int mt = 0; mt < 2; ++mt)
#pragma unroll
        for (int nt = 0; nt < 8; ++nt) {
            const int kg2 = sw * 16 + nt * 2 + (mr >> 3), j2 = mr & 7;
#pragma unroll
            for (int r = 0; r < 4; ++r) {
                const int rl = (w & 1) * 32 + mt * 16 + q * 4 + r;
                Af[(((rl >> 4) * 32 + kg2) * 16 + (rl & 15)) * 8 + j2] = (f16)acc[mt][nt][r];
            }
        }
    __syncthreads();
    const f16* B2 = sred + (size_t)layer * 32768;
    f32x4 a2[8];
#pragma unroll
    for (int nt = 0; nt < 8; ++nt) a2[nt] = (f32x4){0.f, 0.f, 0.f, 0.f};
#pragma unroll
    for (int kt = 0; kt < 8; ++kt) {
        const int kq = kt * 4 + q;
        f16x8 av = *(const f16x8*)&Af[((w * 32 + kq) * 16 + mr) * 8];
        const f16* bp = B2 + ((size_t)kq * HD) * 8;
#pragma unroll
        for (int nt = 0; nt < 8; ++nt) {
            f16x8 bv = *(const f16x8*)(bp + (nt * 16 + mr) * 8);
            a2[nt] = mfma16(av, bv, a2[nt]);
        }
    }
#pragma unroll
    for (int nt = 0; nt < 8; ++nt) {
        const int col = nt * 16 + mr;
        const float bb = bred[layer * HD + col];
#pragma unroll
        for (int r = 0; r < 4; ++r) {
            const int row = row0 + w * 16 + q * 4 + r;
            const float v = a2[nt][r] + bb;
            hiddenf[(size_t)row * HD + col] = v;
            zA[(((size_t)(row >> 4) * 32 + 16 + (col >> 3)) * 16 + (row & 15)) * 8 + (col & 7)] = (f16)v;
        }
    }
}

// ---------------- mean-pool + 2-layer head; float32 output ----------------
__global__ void k_final(const float* hiddenf, const float* Wp1, const float* bp1,
                        const float* Wp2, const float* bp2, float* out) {
    __shared__ float se[128];
    __shared__ float sr[128];
    const int b = blockIdx.x, h = threadIdx.x;
    float acc = 0.f;
    for (int v = 0; v < NNODE; ++v)
        acc += hiddenf[((size_t)b * NNODE + v) * HD + h];
    se[h] = acc * (1.f / 96.f);
    __syncthreads();
    float a2 = bp1[h];
    for (int k = 0; k < 128; ++k)
        a2 += se[k] * Wp1[(size_t)k * HD + h];
    a2 = fmaxf(a2, 0.f);
    sr[h] = a2 * Wp2[h];
    __syncthreads();
    for (int off = 64; off > 0; off >>= 1) {
        if (h < off) sr[h] += sr[h + off];
        __syncthreads();
    }
    if (h == 0) out[b] = sr[0] + bp2[0];
}

extern "C" void kernel_launch(void* const* d_in, const int* in_sizes, int n_in,
                              void* d_out, int out_size, void* d_ws, size_t ws_size,
                              hipStream_t stream) {
    (void)in_sizes; (void)n_in; (void)out_size; (void)ws_size;
    const int* x    = (const int*)d_in[0];
    const int* ea   = (const int*)d_in[1];
    const int* esrc = (const int*)d_in[2];
    const int* edst = (const int*)d_in[3];
    const float* atab = (const float*)d_in[6];
    const float* btab = (const float*)d_in[7];
    const float* Wm1 = (const float*)d_in[8];    const float* bm1 = (const float*)d_in[9];
    const float* Wm2 = (const float*)d_in[10];   const float* bm2 = (const float*)d_in[11];
    const float* Wme = (const float*)d_in[12];   const float* bme = (const float*)d_in[13];
    const float* bmg = (const float*)d_in[15];
    const float* Wmlp1 = (const float*)d_in[16]; const float* bmlp1 = (const float*)d_in[17];
    const float* Wmlp2 = (const float*)d_in[18]; const float* bmlp2 = (const float*)d_in[19];
    const float* Wo1 = (const float*)d_in[20];   const float* bo1 = (const float*)d_in[21];
    const float* Wo2 = (const float*)d_in[22];   const float* bo2 = (const float*)d_in[23];
    const float* lng = (const float*)d_in[24];   const float* lnb = (const float*)d_in[25];
    const float* Wred = (const float*)d_in[26];  const float* bred = (const float*)d_in[27];
    const float* Wp1 = (const float*)d_in[28];   const float* bp1 = (const float*)d_in[29];
    const float* Wp2 = (const float*)d_in[30];   const float* bp2 = (const float*)d_in[31];

    char* cur = (char*)d_ws;
    f16* zA = (f16*)cur;          cur += (size_t)TOTN * 256 * 2;
    float* hiddenf = (float*)cur; cur += (size_t)TOTN * HD * 4;
    f16* eftsA = (f16*)cur;       cur += (size_t)NEDGE * HD * 2;
    f16* emsgP = (f16*)cur;       cur += (size_t)6 * NEDGE * HD * 2;
    float* msg1 = (float*)cur;    cur += (size_t)2 * TOTN * HD * 4;
    float* msg2 = (float*)cur;    cur += (size_t)2 * TOTN * HD * 4;
    float* o1buf = (float*)cur;   cur += (size_t)2 * TOTN * HD * 4;
    float* maxpart = (float*)cur; cur += (size_t)8 * TOTN * HD * 4;
    int* winner = (int*)cur;      cur += (size_t)NG * NNODE * NNODE * 4;
    int* winner2 = (int*)cur;     cur += (size_t)NG * NNODE * NNODE * 4;
    int* eperm = (int*)cur;       cur += (size_t)NEDGE * 4;
    int* cnt = (int*)cur;         cur += (size_t)NREG * 4;
    int* basep = (int*)cur;       cur += (size_t)NREG * 4;
    int* base0 = (int*)cur;       cur += (size_t)NREG * 4;
    f16* sw1 = (f16*)cur;         cur += (size_t)6 * HD * HD * 2;
    f16* sw2 = (f16*)cur;         cur += (size_t)6 * HD * HD * 2;
    f16* swme = (f16*)cur;        cur += (size_t)6 * HD * HD * 2;
    f16* swm1 = (f16*)cur;        cur += (size_t)6 * 256 * HD * 2;
    f16* swm2 = (f16*)cur;        cur += (size_t)6 * 256 * HD * 2;
    f16* swo1 = (f16*)cur;        cur += (size_t)6 * 256 * HD * 2;
    f16* swred = (f16*)cur;       cur += (size_t)3 * 256 * HD * 2;
    f16* swo2 = (f16*)cur;        cur += (size_t)6 * HD * HD * 2;

    const int NPAIR = NG * NNODE * NNODE;
    k_init<<<(NPAIR + 255) / 256, 256, 0, stream>>>(winner, winner2, eperm, cnt);
    k_embed_nodes<<<TOTN, 128, 0, stream>>>(x, atab, zA);
    k_embed_edges<<<NEDGE, 128, 0, stream>>>(ea, btab, eftsA);
    k_winner<<<NEDGE / 256, 256, 0, stream>>>(esrc, edst, winner);
    k_count<<<(NPAIR + 255) / 256, 256, 0, stream>>>(winner, cnt);
    k_scan<<<1, NREG, 0, stream>>>(cnt, basep, base0);
    k_assign<<<(NPAIR + 255) / 256, 256, 0, stream>>>(winner, basep, winner2, eperm);
    k_wswz<<<4224, 256, 0, stream>>>(Wm1, Wm2, Wo1, Wred, Wo2, Wmlp1, Wmlp2, Wme,
                                     swm1, swm2, swo1, swred, swo2, sw1, sw2, swme);
    k_egemm<<<dim3(192, 6), 256, 0, stream>>>(eftsA, swme, eperm, emsgP);
    for (int layer = 0; layer < NLAY; ++layer) {
        k_ngemm<<<dim3(24, 6), 256, 0, stream>>>(zA, swm1, swm2, swo1,
                                                 bm1, bm2, bme, bmg, bo1,
                                                 msg1, msg2, o1buf, layer);
        k_pairs<<<dim3(6, NG, 8), 256, 0, stream>>>(msg1, msg2, emsgP, winner2,
                                                    cnt, base0,
                                                    sw1, bmlp1, sw2, bmlp2,
                                                    maxpart, layer);
        k_pr<<<24, 256, 0, stream>>>(maxpart, o1buf, swo2, bo2, lng, lnb,
                                     swred, bred, hiddenf, zA, layer);
    }
    k_final<<<NG, 128, 0, stream>>>(hiddenf, Wp1, bp1, Wp2, bp2, (float*)d_out);
}

// Round 18
// 420.174 us; speedup vs baseline: 1.2732x; 1.2035x over previous
//
#include <hip/hip_runtime.h>
#include <cstddef>

typedef _Float16 f16;
typedef f16 f16x8 __attribute__((ext_vector_type(8)));
typedef f16 f16x4 __attribute__((ext_vector_type(4)));
typedef float f32x4 __attribute__((ext_vector_type(4)));

constexpr int NG    = 16;
constexpr int NNODE = 96;
constexpr int TOTN  = 1536;
constexpr int HD    = 128;
constexpr int NEDGE = 24576;
constexpr int NLAY  = 3;
constexpr int NPAIR = NG * NNODE * NNODE;  // 147456
constexpr int NREG  = NG * 6 * 12;         // 1152 regions (b, jt, 8-i chunk)
constexpr int EMCAP = 64;                  // LDS edge-window cap (region mean ~20, max ~40)
constexpr int EMSTR = 132;                 // padded f16 row stride

__device__ __forceinline__ f32x4 mfma16(f16x8 a, f16x8 b, f32x4 c) {
    return __builtin_amdgcn_mfma_f32_16x16x32_f16(a, b, c, 0, 0, 0);
}

// ---- merged prep: init + node embed (zA) + edge embed (eftsA) + weight swizzle ----
// blocks: [0,576) init | [576,1344) nodes | [1344,13632) edges | [13632,17856) swizzle
__global__ __launch_bounds__(256) void k_prep(
    const int* x, const float* atab, const int* ea, const float* btab,
    const float* Wm1, const float* Wm2, const float* Wo1, const float* Wred,
    const float* Wo2, const float* W1, const float* W2, const float* We,
    f16* zA, f16* eftsA, int* winner, int* winner2, int* eperm, int* cnt,
    f16* sm1, f16* sm2, f16* so1, f16* sred, f16* so2, f16* s1, f16* s2, f16* sme) {
    const int blk = blockIdx.x, tid = threadIdx.x;
    if (blk < 576) {  // init (guarded! NPAIR = 576*256 exactly)
        const int idx = blk * 256 + tid;
        if (idx < NPAIR) {
            winner[idx] = -1;
            winner2[idx] = -1;
        }
        if (idx < NEDGE) eperm[idx] = -1;
        if (idx < NREG) cnt[idx] = 0;
        return;
    }
    if (blk < 576 + 768) {  // node embeddings (2 nodes per block)
        const int v = (blk - 576) * 2 + (tid >> 7), h = tid & 127;
        float s = 0.f;
        for (int c = 0; c < 9; ++c)
            s += atab[((size_t)(c * 119 + x[v * 9 + c])) * HD + h];
        const size_t base = ((size_t)(v >> 4) * 32);
        zA[((base + (h >> 3)) * 16 + (v & 15)) * 8 + (h & 7)] = (f16)s;
        zA[((base + 16 + (h >> 3)) * 16 + (v & 15)) * 8 + (h & 7)] = (f16)0.f;
        return;
    }
    if (blk < 576 + 768 + 12288) {  // edge embeddings (2 edges per block)
        const int e = (blk - 576 - 768) * 2 + (tid >> 7), h = tid & 127;
        float s = 0.f;
        for (int c = 0; c < 3; ++c)
            s += btab[((size_t)(c * 6 + ea[e * 3 + c])) * HD + h];
        eftsA[(((size_t)(e >> 4) * 16 + (h >> 3)) * 16 + (e & 15)) * 8 + (h & 7)] = (f16)s;
        return;
    }
    // weight swizzle
    const int idx = (blk - 576 - 768 - 12288) * 256 + tid;
    const int S256 = 6 * 256 * 128, SRED = 3 * 256 * 128, S128 = 6 * 128 * 128;
    const float* src;
    f16* dst;
    int rel, sh;
    if (idx < S256)                 { src = Wm1;  dst = sm1;  rel = idx;            sh = 15; }
    else if (idx < 2 * S256)        { src = Wm2;  dst = sm2;  rel = idx - S256;     sh = 15; }
    else if (idx < 3 * S256)        { src = Wo1;  dst = so1;  rel = idx - 2 * S256; sh = 15; }
    else if (idx < 3 * S256 + SRED) { src = Wred; dst = sred; rel = idx - 3 * S256; sh = 15; }
    else if (idx < 3 * S256 + SRED + S128)
        { src = Wo2; dst = so2; rel = idx - 3 * S256 - SRED; sh = 14; }
    else if (idx < 3 * S256 + SRED + 2 * S128)
        { src = W1;  dst = s1;  rel = idx - 3 * S256 - SRED - S128; sh = 14; }
    else if (idx < 3 * S256 + SRED + 3 * S128)
        { src = W2;  dst = s2;  rel = idx - 3 * S256 - SRED - 2 * S128; sh = 14; }
    else if (idx < 3 * S256 + SRED + 4 * S128)
        { src = We;  dst = sme; rel = idx - 3 * S256 - SRED - 3 * S128; sh = 14; }
    else return;
    const int mat = rel >> sh;
    const int r2 = rel & ((1 << sh) - 1);
    const int k = r2 >> 7, n = r2 & 127;
    dst[(size_t)mat * (1 << sh) + (((k >> 3) * 128 + n) << 3) + (k & 7)] = (f16)src[rel];
}

// last-write-wins: largest edge id wins (numpy fancy-assignment semantics)
__global__ void k_winner(const int* esrc, const int* edst, int* winner) {
    const int e = blockIdx.x * 256 + threadIdx.x;
    const int sg = esrc[e];
    const int g = sg / NNODE;
    const int li = sg - g * NNODE;
    const int lj = edst[e] - g * NNODE;
    atomicMax(&winner[((size_t)g * NNODE + li) * NNODE + lj], e);
}

__device__ __forceinline__ int region_of(int idx) {
    const int b = idx / (NNODE * NNODE);
    const int r = idx - b * NNODE * NNODE;
    const int i = r / NNODE, j = r - (r / NNODE) * NNODE;
    return b * 72 + (j >> 4) * 12 + (i >> 3);
}

__global__ void k_count(const int* winner, int* cnt) {
    const int idx = blockIdx.x * 256 + threadIdx.x;
    if (idx < NPAIR && winner[idx] >= 0)
        atomicAdd(&cnt[region_of(idx)], 1);
}

// exclusive scan over 1152 region counts: 576 threads x 2 regions
__global__ void k_scan(const int* cnt, int* base, int* base0) {
    __shared__ int tmp[576];
    const int t = threadIdx.x;
    const int c0 = cnt[2 * t], c1 = cnt[2 * t + 1];
    tmp[t] = c0 + c1;
    __syncthreads();
    for (int off = 1; off < 576; off <<= 1) {
        int v = (t >= off) ? tmp[t - off] : 0;
        __syncthreads();
        tmp[t] += v;
        __syncthreads();
    }
    const int ex = tmp[t] - (c0 + c1);
    base[2 * t] = ex;          base0[2 * t] = ex;
    base[2 * t + 1] = ex + c0; base0[2 * t + 1] = ex + c0;
}

__global__ void k_assign(const int* winner, int* base, int* winner2, int* eperm) {
    const int idx = blockIdx.x * 256 + threadIdx.x;
    if (idx >= NPAIR) return;
    const int e = winner[idx];
    if (e >= 0) {
        const int p = atomicAdd(&base[region_of(idx)], 1);
        winner2[idx] = p;
        eperm[e] = p;
    }
}

// ------- per-node GEMMs via MFMA (streaming zA): msg1' / msg2 / o1 -------
__global__ __launch_bounds__(256) void k_ngemm(
    const f16* __restrict__ zA,
    const f16* __restrict__ sm1, const f16* __restrict__ sm2, const f16* __restrict__ so1,
    const float* __restrict__ bm1, const float* __restrict__ bm2,
    const float* __restrict__ bme, const float* __restrict__ bmg,
    const float* __restrict__ bo1,
    float* __restrict__ msg1, float* __restrict__ msg2, float* __restrict__ o1buf,
    int layer) {
    const int tid = threadIdx.x, lane = tid & 63, w = tid >> 6;
    const int mr = lane & 15, q = lane >> 4;
    const int t0 = blockIdx.x;
    const int wh = blockIdx.y >> 1, s = blockIdx.y & 1, ls = layer * 2 + s;
    const f16* B;
    float* out;
    float bias[8];
    if (wh == 0) {
        B = sm1 + (size_t)ls * 32768; out = msg1 + (size_t)s * TOTN * HD;
        for (int nt = 0; nt < 8; ++nt) {
            const int col = nt * 16 + mr;
            bias[nt] = bm1[ls * HD + col] + bme[ls * HD + col] + bmg[ls * HD + col];
        }
    } else if (wh == 1) {
        B = sm2 + (size_t)ls * 32768; out = msg2 + (size_t)s * TOTN * HD;
        for (int nt = 0; nt < 8; ++nt) bias[nt] = bm2[ls * HD + nt * 16 + mr];
    } else {
        B = so1 + (size_t)ls * 32768; out = o1buf + (size_t)s * TOTN * HD;
        for (int nt = 0; nt < 8; ++nt) bias[nt] = bo1[ls * HD + nt * 16 + mr];
    }
    const size_t tIdx = (size_t)t0 * 4 + w;
    f32x4 acc[8];
#pragma unroll
    for (int nt = 0; nt < 8; ++nt) acc[nt] = (f32x4){0.f, 0.f, 0.f, 0.f};
#pragma unroll
    for (int kt = 0; kt < 8; ++kt) {
        const int kq = kt * 4 + q;
        f16x8 a = *(const f16x8*)&zA[((tIdx * 32 + kq) * 16 + mr) * 8];
        const f16* bp = B + ((size_t)kq * HD) * 8;
#pragma unroll
        for (int nt = 0; nt < 8; ++nt) {
            f16x8 bv = *(const f16x8*)(bp + (nt * 16 + mr) * 8);
            acc[nt] = mfma16(a, bv, acc[nt]);
        }
    }
#pragma unroll
    for (int nt = 0; nt < 8; ++nt) {
        const int col = nt * 16 + mr;
#pragma unroll
        for (int r = 0; r < 4; ++r) {
            const int row = t0 * 64 + w * 16 + q * 4 + r;
            out[(size_t)row * HD + col] = acc[nt][r] + bias[nt];
        }
    }
}

// ------- per-edge GEMM (ALL 6 mats): emsgP[ls][p] = (eftsA @ Wme)[winning e] -------
__global__ __launch_bounds__(256) void k_egemm(
    const f16* __restrict__ eftsA, const f16* __restrict__ sme,
    const int* __restrict__ eperm, f16* __restrict__ emsgP) {
    const int tid = threadIdx.x, lane = tid & 63, w = tid >> 6;
    const int mr = lane & 15, q = lane >> 4;
    const int ls = blockIdx.y;
    const f16* B = sme + (size_t)ls * 16384;
    f32x4 acc[2][8];
#pragma unroll
    for (int mt = 0; mt < 2; ++mt)
#pragma unroll
        for (int nt = 0; nt < 8; ++nt) acc[mt][nt] = (f32x4){0.f, 0.f, 0.f, 0.f};
#pragma unroll
    for (int kt = 0; kt < 4; ++kt) {
        const int kq = kt * 4 + q;
        f16x8 a0 = *(const f16x8*)&eftsA[(((size_t)(blockIdx.x * 8 + 2 * w + 0) * 16 + kq) * 16 + mr) * 8];
        f16x8 a1 = *(const f16x8*)&eftsA[(((size_t)(blockIdx.x * 8 + 2 * w + 1) * 16 + kq) * 16 + mr) * 8];
        const f16* bp = B + ((size_t)kq * HD) * 8;
#pragma unroll
        for (int nt = 0; nt < 8; ++nt) {
            f16x8 bv = *(const f16x8*)(bp + (nt * 16 + mr) * 8);
            acc[0][nt] = mfma16(a0, bv, acc[0][nt]);
            acc[1][nt] = mfma16(a1, bv, acc[1][nt]);
        }
    }
#pragma unroll
    for (int mt = 0; mt < 2; ++mt) {
        const int ebase = blockIdx.x * 128 + (2 * w + mt) * 16 + q * 4;
#pragma unroll
        for (int r = 0; r < 4; ++r) {
            const int p = eperm[ebase + r];
            if (p < 0) continue;
            f16* orow = emsgP + ((size_t)ls * NEDGE + p) * HD;
#pragma unroll
            for (int nt = 0; nt < 8; ++nt)
                orow[nt * 16 + mr] = (f16)acc[mt][nt][r];
        }
    }
}

// ---------- pair MLP v7: single 8-i octet per block, LDS window, no flat ----------
// grid (6 jt, NG, 24 zz=cp*2+s); 256 thr; LDS 51.7 KB.
__global__ __launch_bounds__(256) void k_pairs(
    const float* __restrict__ msg1, const float* __restrict__ msg2,
    const f16* __restrict__ emsgP, const int* __restrict__ winner2,
    const int* __restrict__ cnt0, const int* __restrict__ base0,
    const f16* __restrict__ w1s, const float* __restrict__ bmlp1,
    const f16* __restrict__ w2s, const float* __restrict__ bmlp2,
    f16* __restrict__ maxpart, int layer) {
    __shared__ __align__(16) f16 EMs[EMCAP * EMSTR];  // 16.9 KB
    __shared__ __align__(16) f16 M2s[8 * 128];        // 2 KB
    __shared__ __align__(16) f16 Qb[128 * 128];       // 32 KB
    const int tid = threadIdx.x, lane = tid & 63, w = tid >> 6;
    const int mr = lane & 15, q = lane >> 4;
    const int jt = blockIdx.x, b = blockIdx.y, zz = blockIdx.z;
    const int cp = zz >> 1, s = zz & 1, ls = layer * 2 + s;
    const int j0 = jt * 16, i0 = cp * 8;
    const f16* EM = emsgP + (size_t)ls * NEDGE * HD;
    const f16* W1 = w1s + (size_t)ls * HD * HD;
    const f16* W2 = w2s + (size_t)ls * HD * HD;
    const int reg = b * 72 + jt * 12 + cp;
    const int rbase = base0[reg];
    const int rcnt = cnt0[reg];
    // ---- stream edge window into LDS (contiguous after permutation) ----
    {
        const int lim = (rcnt < EMCAP ? rcnt : EMCAP) * 16;
        for (int idx = tid; idx < lim; idx += 256) {
            const int row = idx >> 4, seg = idx & 15;
            *(f16x8*)&EMs[row * EMSTR + seg * 8] =
                *(const f16x8*)&EM[((size_t)(rbase + row)) * HD + seg * 8];
        }
    }
    // ---- msg2 rows i0..i0+7 to LDS (f16) ----
    {
        const int row = tid >> 5, c4 = (tid & 31) * 4;
        float4 v = *(const float4*)&msg2[((size_t)s * TOTN + b * NNODE + i0 + row) * HD + c4];
        f16x4 h;
        h[0] = (f16)v.x; h[1] = (f16)v.y; h[2] = (f16)v.z; h[3] = (f16)v.w;
        *(f16x4*)&M2s[row * 128 + c4] = h;
    }
    // ---- msg1 fragment (per-lane invariant): j = j0+mr ----
    f16x8 m1f[4];
    {
        const float* m1p = msg1 + ((size_t)s * TOTN + b * NNODE + j0 + mr) * HD;
#pragma unroll
        for (int kt = 0; kt < 4; ++kt) {
            float4 p0 = *(const float4*)(m1p + kt * 32 + q * 8);
            float4 p1 = *(const float4*)(m1p + kt * 32 + q * 8 + 4);
            m1f[kt][0] = (f16)p0.x; m1f[kt][1] = (f16)p0.y;
            m1f[kt][2] = (f16)p0.z; m1f[kt][3] = (f16)p0.w;
            m1f[kt][4] = (f16)p1.x; m1f[kt][5] = (f16)p1.y;
            m1f[kt][6] = (f16)p1.z; m1f[kt][7] = (f16)p1.w;
        }
    }
    // ---- GEMM1 B fragments in registers (W2 comes from L2 later) ----
    f16x8 Bf1[4][2];
#pragma unroll
    for (int kt = 0; kt < 4; ++kt)
#pragma unroll
        for (int ntl = 0; ntl < 2; ++ntl)
            Bf1[kt][ntl] = *(const f16x8*)(W1 +
                ((size_t)(kt * 4 + q) * 128 + (2 * w + ntl) * 16 + mr) * 8);
    float b1v[2], b2v[2];
#pragma unroll
    for (int ntl = 0; ntl < 2; ++ntl) {
        const int col = (2 * w + ntl) * 16 + mr;
        b1v[ntl] = bmlp1[ls * HD + col];
        b2v[ntl] = bmlp2[ls * HD + col];
    }
    int wv[8];
#pragma unroll
    for (int mt = 0; mt < 8; ++mt)
        wv[mt] = winner2[((size_t)b * NNODE + i0 + mt) * NNODE + j0 + mr];
    __syncthreads();  // EMs + M2s ready
    // ---- GEMM1 with register-built A = relu(m1 + m2 + e) ----
    f32x4 acc[8][2];
#pragma unroll
    for (int mt = 0; mt < 8; ++mt)
#pragma unroll
        for (int ntl = 0; ntl < 2; ++ntl) acc[mt][ntl] = (f32x4){0.f, 0.f, 0.f, 0.f};
#pragma unroll
    for (int kt = 0; kt < 4; ++kt) {
        const int ko = kt * 32 + q * 8;
#pragma unroll
        for (int mt = 0; mt < 8; ++mt) {
            f16x8 m2v = *(const f16x8*)&M2s[mt * 128 + ko];
            f16x8 av = m1f[kt] + m2v;
            if (wv[mt] >= 0) {
                const int lp = wv[mt] - rbase;
                f16x8 ev;
                if (lp < EMCAP) ev = *(const f16x8*)&EMs[lp * EMSTR + ko];         // ds_read
                else            ev = *(const f16x8*)&EM[(size_t)wv[mt] * HD + ko]; // global
                av = av + ev;
            }
#pragma unroll
            for (int u = 0; u < 8; ++u)
                av[u] = av[u] > (f16)0.f ? av[u] : (f16)0.f;
            acc[mt][0] = mfma16(av, Bf1[kt][0], acc[mt][0]);
            acc[mt][1] = mfma16(av, Bf1[kt][1], acc[mt][1]);
        }
    }
    // ---- write Q = relu(acc + b1) into Qb ----
#pragma unroll
    for (int mt = 0; mt < 8; ++mt)
#pragma unroll
        for (int ntl = 0; ntl < 2; ++ntl) {
            const int col = (2 * w + ntl) * 16 + mr;
            const int kg = col >> 3, kj = col & 7;
#pragma unroll
            for (int r = 0; r < 4; ++r) {
                float v = fmaxf(acc[mt][ntl][r] + b1v[ntl], 0.f);
                Qb[((mt * 16 + kg) * 16 + q * 4 + r) * 8 + kj] = (f16)v;
            }
        }
    __syncthreads();
    // ---- GEMM2 (W2 from L2) + max over 8 i ----
#pragma unroll
    for (int mt = 0; mt < 8; ++mt)
#pragma unroll
        for (int ntl = 0; ntl < 2; ++ntl) acc[mt][ntl] = (f32x4){0.f, 0.f, 0.f, 0.f};
#pragma unroll
    for (int kt = 0; kt < 4; ++kt) {
        f16x8 bv0 = *(const f16x8*)(W2 + ((size_t)(kt * 4 + q) * 128 + (2 * w + 0) * 16 + mr) * 8);
        f16x8 bv1 = *(const f16x8*)(W2 + ((size_t)(kt * 4 + q) * 128 + (2 * w + 1) * 16 + mr) * 8);
#pragma unroll
        for (int mt = 0; mt < 8; ++mt) {
            f16x8 a = *(const f16x8*)&Qb[((mt * 16 + kt * 4 + q) * 16 + mr) * 8];
            acc[mt][0] = mfma16(a, bv0, acc[mt][0]);
            acc[mt][1] = mfma16(a, bv1, acc[mt][1]);
        }
    }
#pragma unroll
    for (int ntl = 0; ntl < 2; ++ntl) {
        const int col = (2 * w + ntl) * 16 + mr;
#pragma unroll
        for (int r = 0; r < 4; ++r) {
            float m0 = acc[0][ntl][r];
#pragma unroll
            for (int mt = 1; mt < 8; ++mt) m0 = fmaxf(m0, acc[mt][ntl][r]);
            const int j = j0 + q * 4 + r;
            maxpart[((size_t)zz * TOTN + b * NNODE + j) * HD + col] = (f16)(m0 + b2v[ntl]);
        }
    }
}

// ---- fused MFMA: maxreduce(24 f16 slices) -> o2 GEMM -> LN -> red GEMM ----
__global__ __launch_bounds__(256) void k_pr(
    const f16* __restrict__ maxpart, const float* __restrict__ o1buf,
    const f16* __restrict__ so2, const float* __restrict__ bo2,
    const float* __restrict__ lng, const float* __restrict__ lnb,
    const f16* __restrict__ sred, const float* __restrict__ bred,
    float* __restrict__ hiddenf, f16* __restrict__ zA, int layer) {
    __shared__ __align__(16) f16 Af[16384];  // 32 KB, time-shared A1/A2
    const int tid = threadIdx.x, lane = tid & 63, w = tid >> 6;
    const int mr = lane & 15, q = lane >> 4;
    const int row0 = blockIdx.x * 64;
    {
        const int mrow = tid >> 1, half = tid & 1;
        const int sb = mrow >> 6, rl = mrow & 63;
        const int row = row0 + rl;
#pragma unroll
        for (int c8 = 0; c8 < 64; c8 += 8) {
            const int col = half * 64 + c8;
            f16x8 mx = *(const f16x8*)&maxpart[((size_t)(0 * 2 + sb) * TOTN + row) * HD + col];
#pragma unroll
            for (int cp = 1; cp < 12; ++cp) {
                f16x8 v = *(const f16x8*)&maxpart[((size_t)(cp * 2 + sb) * TOTN + row) * HD + col];
#pragma unroll
                for (int u = 0; u < 8; ++u) mx[u] = mx[u] > v[u] ? mx[u] : v[u];
            }
            *(f16x8*)&Af[(((sb * 4 + (rl >> 4)) * 16 + (col >> 3)) * 16 + (rl & 15)) * 8] = mx;
        }
    }
    __syncthreads();
    const int sw = w >> 1, ls = layer * 2 + sw;
    const f16* B1 = so2 + (size_t)ls * 16384;
    f32x4 acc[2][8];
#pragma unroll
    for (int mt = 0; mt < 2; ++mt)
#pragma unroll
        for (int nt = 0; nt < 8; ++nt) acc[mt][nt] = (f32x4){0.f, 0.f, 0.f, 0.f};
#pragma unroll
    for (int kt = 0; kt < 4; ++kt) {
        const int kq = kt * 4 + q;
        f16x8 a0 = *(const f16x8*)&Af[(((sw * 4 + (w & 1) * 2 + 0) * 16 + kq) * 16 + mr) * 8];
        f16x8 a1 = *(const f16x8*)&Af[(((sw * 4 + (w & 1) * 2 + 1) * 16 + kq) * 16 + mr) * 8];
        const f16* bp = B1 + ((size_t)kq * HD) * 8;
#pragma unroll
        for (int nt = 0; nt < 8; ++nt) {
            f16x8 bv = *(const f16x8*)(bp + (nt * 16 + mr) * 8);
            acc[0][nt] = mfma16(a0, bv, acc[0][nt]);
            acc[1][nt] = mfma16(a1, bv, acc[1][nt]);
        }
    }
    float lngv[8], lnbv[8], bo2v[8];
#pragma unroll
    for (int nt = 0; nt < 8; ++nt) {
        const int col = nt * 16 + mr;
        lngv[nt] = lng[ls * HD + col];
        lnbv[nt] = lnb[ls * HD + col];
        bo2v[nt] = bo2[ls * HD + col];
    }
#pragma unroll
    for (int mt = 0; mt < 2; ++mt) {
#pragma unroll
        for (int nt = 0; nt < 8; ++nt) {
            const int col = nt * 16 + mr;
#pragma unroll
            for (int r = 0; r < 4; ++r) {
                const int rl = (w & 1) * 32 + mt * 16 + q * 4 + r;
                float v = acc[mt][nt][r] + bo2v[nt] +
                          o1buf[((size_t)sw * TOTN + row0 + rl) * HD + col];
                acc[mt][nt][r] = fmaxf(v, 0.f);
            }
        }
#pragma unroll
        for (int r = 0; r < 4; ++r) {
            float su = 0.f, sq = 0.f;
#pragma unroll
            for (int nt = 0; nt < 8; ++nt) {
                su += acc[mt][nt][r];
                sq += acc[mt][nt][r] * acc[mt][nt][r];
            }
#pragma unroll
            for (int mask = 1; mask <= 8; mask <<= 1) {
                su += __shfl_xor(su, mask, 64);
                sq += __shfl_xor(sq, mask, 64);
            }
            const float mean = su * (1.f / 128.f);
            float var = sq * (1.f / 128.f) - mean * mean;
            var = fmaxf(var, 0.f);
            const float rstd = 1.f / sqrtf(var + 1e-5f);
#pragma unroll
            for (int nt = 0; nt < 8; ++nt)
                acc[mt][nt][r] = (acc[mt][nt][r] - mean) * rstd * lngv[nt] + lnbv[nt];
        }
    }
    __syncthreads();
#pragma unroll
    for (int mt = 0; mt < 2; ++mt)
#pragma unroll
        for (int nt = 0; nt < 8; ++nt) {
            const int kg2 = sw * 16 + nt * 2 + (mr >> 3), j2 = mr & 7;
#pragma unroll
            for (int r = 0; r < 4; ++r) {
                const int rl = (w & 1) * 32 + mt * 16 + q * 4 + r;
                Af[(((rl >> 4) * 32 + kg2) * 16 + (rl & 15)) * 8 + j2] = (f16)acc[mt][nt][r];
            }
        }
    __syncthreads();
    const f16* B2 = sred + (size_t)layer * 32768;
    f32x4 a2[8];
#pragma unroll
    for (int nt = 0; nt < 8; ++nt) a2[nt] = (f32x4){0.f, 0.f, 0.f, 0.f};
#pragma unroll
    for (int kt = 0; kt < 8; ++kt) {
        const int kq = kt * 4 + q;
        f16x8 av = *(const f16x8*)&Af[((w * 32 + kq) * 16 + mr) * 8];
        const f16* bp = B2 + ((size_t)kq * HD) * 8;
#pragma unroll
        for (int nt = 0; nt < 8; ++nt) {
            f16x8 bv = *(const f16x8*)(bp + (nt * 16 + mr) * 8);
            a2[nt] = mfma16(av, bv, a2[nt]);
        }
    }
#pragma unroll
    for (int nt = 0; nt < 8; ++nt) {
        const int col = nt * 16 + mr;
        const float bb = bred[layer * HD + col];
#pragma unroll
        for (int r = 0; r < 4; ++r) {
            const int row = row0 + w * 16 + q * 4 + r;
            const float v = a2[nt][r] + bb;
            hiddenf[(size_t)row * HD + col] = v;
            zA[(((size_t)(row >> 4) * 32 + 16 + (col >> 3)) * 16 + (row & 15)) * 8 + (col & 7)] = (f16)v;
        }
    }
}

// ---------------- mean-pool + 2-layer head; float32 output ----------------
__global__ void k_final(const float* hiddenf, const float* Wp1, const float* bp1,
                        const float* Wp2, const float* bp2, float* out) {
    __shared__ float se[128];
    __shared__ float sr[128];
    const int b = blockIdx.x, h = threadIdx.x;
    float acc = 0.f;
    for (int v = 0; v < NNODE; ++v)
        acc += hiddenf[((size_t)b * NNODE + v) * HD + h];
    se[h] = acc * (1.f / 96.f);
    __syncthreads();
    float a2 = bp1[h];
    for (int k = 0; k < 128; ++k)
        a2 += se[k] * Wp1[(size_t)k * HD + h];
    a2 = fmaxf(a2, 0.f);
    sr[h] = a2 * Wp2[h];
    __syncthreads();
    for (int off = 64; off > 0; off >>= 1) {
        if (h < off) sr[h] += sr[h + off];
        __syncthreads();
    }
    if (h == 0) out[b] = sr[0] + bp2[0];
}

extern "C" void kernel_launch(void* const* d_in, const int* in_sizes, int n_in,
                              void* d_out, int out_size, void* d_ws, size_t ws_size,
                              hipStream_t stream) {
    (void)in_sizes; (void)n_in; (void)out_size; (void)ws_size;
    const int* x    = (const int*)d_in[0];
    const int* ea   = (const int*)d_in[1];
    const int* esrc = (const int*)d_in[2];
    const int* edst = (const int*)d_in[3];
    const float* atab = (const float*)d_in[6];
    const float* btab = (const float*)d_in[7];
    const float* Wm1 = (const float*)d_in[8];    const float* bm1 = (const float*)d_in[9];
    const float* Wm2 = (const float*)d_in[10];   const float* bm2 = (const float*)d_in[11];
    const float* Wme = (const float*)d_in[12];   const float* bme = (const float*)d_in[13];
    const float* bmg = (const float*)d_in[15];
    const float* Wmlp1 = (const float*)d_in[16]; const float* bmlp1 = (const float*)d_in[17];
    const float* Wmlp2 = (const float*)d_in[18]; const float* bmlp2 = (const float*)d_in[19];
    const float* Wo1 = (const float*)d_in[20];   const float* bo1 = (const float*)d_in[21];
    const float* Wo2 = (const float*)d_in[22];   const float* bo2 = (const float*)d_in[23];
    const float* lng = (const float*)d_in[24];   const float* lnb = (const float*)d_in[25];
    const float* Wred = (const float*)d_in[26];  const float* bred = (const float*)d_in[27];
    const float* Wp1 = (const float*)d_in[28];   const float* bp1 = (const float*)d_in[29];
    const float* Wp2 = (const float*)d_in[30];   const float* bp2 = (const float*)d_in[31];

    char* cur = (char*)d_ws;
    f16* zA = (f16*)cur;          cur += (size_t)TOTN * 256 * 2;
    float* hiddenf = (float*)cur; cur += (size_t)TOTN * HD * 4;
    f16* eftsA = (f16*)cur;       cur += (size_t)NEDGE * HD * 2;
    f16* emsgP = (f16*)cur;       cur += (size_t)6 * NEDGE * HD * 2;
    float* msg1 = (float*)cur;    cur += (size_t)2 * TOTN * HD * 4;
    float* msg2 = (float*)cur;    cur += (size_t)2 * TOTN * HD * 4;
    float* o1buf = (float*)cur;   cur += (size_t)2 * TOTN * HD * 4;
    f16* maxpart = (f16*)cur;     cur += (size_t)24 * TOTN * HD * 2;
    int* winner = (int*)cur;      cur += (size_t)NPAIR * 4;
    int* winner2 = (int*)cur;     cur += (size_t)NPAIR * 4;
    int* eperm = (int*)cur;       cur += (size_t)NEDGE * 4;
    int* cnt = (int*)cur;         cur += (size_t)NREG * 4;
    int* basep = (int*)cur;       cur += (size_t)NREG * 4;
    int* base0 = (int*)cur;       cur += (size_t)NREG * 4;
    f16* sw1 = (f16*)cur;         cur += (size_t)6 * HD * HD * 2;
    f16* sw2 = (f16*)cur;         cur += (size_t)6 * HD * HD * 2;
    f16* swme = (f16*)cur;        cur += (size_t)6 * HD * HD * 2;
    f16* swm1 = (f16*)cur;        cur += (size_t)6 * 256 * HD * 2;
    f16* swm2 = (f16*)cur;        cur += (size_t)6 * 256 * HD * 2;
    f16* swo1 = (f16*)cur;        cur += (size_t)6 * 256 * HD * 2;
    f16* swred = (f16*)cur;       cur += (size_t)3 * 256 * HD * 2;
    f16* swo2 = (f16*)cur;        cur += (size_t)6 * HD * HD * 2;

    k_prep<<<576 + 768 + 12288 + 4224, 256, 0, stream>>>(
        x, atab, ea, btab, Wm1, Wm2, Wo1, Wred, Wo2, Wmlp1, Wmlp2, Wme,
        zA, eftsA, winner, winner2, eperm, cnt,
        swm1, swm2, swo1, swred, swo2, sw1, sw2, swme);
    k_winner<<<NEDGE / 256, 256, 0, stream>>>(esrc, edst, winner);
    k_count<<<(NPAIR + 255) / 256, 256, 0, stream>>>(winner, cnt);
    k_scan<<<1, 576, 0, stream>>>(cnt, basep, base0);
    k_assign<<<(NPAIR + 255) / 256, 256, 0, stream>>>(winner, basep, winner2, eperm);
    k_egemm<<<dim3(192, 6), 256, 0, stream>>>(eftsA, swme, eperm, emsgP);
    for (int layer = 0; layer < NLAY; ++layer) {
        k_ngemm<<<dim3(24, 6), 256, 0, stream>>>(zA, swm1, swm2, swo1,
                                                 bm1, bm2, bme, bmg, bo1,
                                                 msg1, msg2, o1buf, layer);
        k_pairs<<<dim3(6, NG, 24), 256, 0, stream>>>(msg1, msg2, emsgP, winner2,
                                                     cnt, base0,
                                                     sw1, bmlp1, sw2, bmlp2,
                                                     maxpart, layer);
        k_pr<<<24, 256, 0, stream>>>(maxpart, o1buf, swo2, bo2, lng, lnb,
                                     swred, bred, hiddenf, zA, layer);
    }
    k_final<<<NG, 128, 0, stream>>>(hiddenf, Wp1, bp1, Wp2, bp2, (float*)d_out);
}